// Round 3
// baseline (909.704 us; speedup 1.0000x reference)
//
#include <hip/hip_runtime.h>
#include <hip/hip_bf16.h>
#include <math.h>

typedef __bf16 bf16_t;
typedef __bf16 bf16x8 __attribute__((ext_vector_type(8)));
typedef __bf16 bf16x4 __attribute__((ext_vector_type(4)));
typedef float  floatx4 __attribute__((ext_vector_type(4)));

#define NB 512      // batch
#define DI 256      // feature dim
#define TM 32       // GEMM rows per block
#define CHUNK 512   // max K elems of A staged in LDS

__device__ __forceinline__ float lrelu_f(float x){ return x >= 0.f ? x : 0.2f*x; }
__device__ __forceinline__ float elu_f(float x){ return x > 0.f ? x : expm1f(x); }

// ---------------- small fp32 buffers (biases, attn vecs) -> bf16 ws -----------
struct SCEnt { const float* s; bf16_t* d; int n; };
struct SCArgs { SCEnt e[16]; int cnt; };

__global__ __launch_bounds__(256)
void smallconv_k(SCArgs a)
{
    for (int k = 0; k < a.cnt; ++k) {
        int n = a.e[k].n;
        for (int i = threadIdx.x; i < n; i += 256)
            a.e[k].d[i] = (bf16_t)a.e[k].s[i];
    }
}

// ---------------- batched fp32->bf16 transposes: WT[n][k] = W[eoff + k*256+n] -
struct TJob { const float* W; bf16_t* WT; int K; int eoff; int tbase; };
struct TJobs { TJob j[15]; };

__global__ __launch_bounds__(256)
void transpose_all_k(TJobs tj, int njobs)
{
    int tile = blockIdx.x;
    int ji = 0;
    for (int i = 1; i < njobs; ++i) if (tile >= tj.j[i].tbase) ji = i;
    TJob jb = tj.j[ji];
    int local = tile - jb.tbase;
    int tiles_x = jb.K >> 5;
    int kb = (local % tiles_x) * 32;
    int nb = (local / tiles_x) * 32;

    __shared__ bf16_t ts[32][33];
    int tx = threadIdx.x & 31, ty = threadIdx.x >> 5;
    #pragma unroll
    for (int rr = 0; rr < 4; ++rr) {
        int r = ty + rr * 8;
        ts[r][tx] = (bf16_t)jb.W[(size_t)jb.eoff + (size_t)(kb + r) * 256 + nb + tx];
    }
    __syncthreads();
    #pragma unroll
    for (int rr = 0; rr < 4; ++rr) {
        int r = ty + rr * 8;
        jb.WT[(size_t)(nb + r) * jb.K + kb + tx] = ts[tx][r];
    }
}

// ---------------- streaming MFMA GEMM -----------------------------------------
// out[row_remap(m), n] = sum_k A[in_remap(m), k] * WT[n, k]  (+ bias[n])
// Block: TM=32 rows x all N=256 cols (4 waves x 64 cols). A staged to LDS in
// row-contiguous order (fp32->bf16 convert, XOR granule swizzle), K chunks of
// <=512. B frags are wave-private: per-lane 16B loads straight from L2-hot WT
// with depth-2 register prefetch -> the inner K loop has NO barriers.
__global__ __launch_bounds__(256)
void gemm2_k(const void* __restrict__ A, int Kin,
             int isb, int ioff, int rpb, int a_fp32,
             const bf16_t* __restrict__ WT,     // [256, Kin]
             const bf16_t* __restrict__ bias,   // [256] bf16 or nullptr
             bf16_t* __restrict__ out, int osb, int ooff)
{
    __shared__ bf16_t As[TM * CHUNK];           // 32 KB

    const int t = threadIdx.x;
    const int m0 = blockIdx.x * TM;
    const int lane = t & 63, wave = t >> 6;
    const int lm = lane & 15, kq = lane >> 4;
    const int n0w = wave * 64;

    const int chunk = (Kin < CHUNK) ? Kin : CHUNK;
    const int gsh = (chunk == CHUNK) ? 6 : 5;   // log2(granules per row)
    const int gm = (chunk >> 3) - 1;
    const int nch = Kin / chunk;
    const int spc = chunk >> 5;                 // k32 steps per chunk
    const int tsteps = Kin >> 5;

    const bf16_t* wrow0 = WT + (size_t)(n0w      + lm) * Kin + kq * 8;
    const bf16_t* wrow1 = WT + (size_t)(n0w + 16 + lm) * Kin + kq * 8;
    const bf16_t* wrow2 = WT + (size_t)(n0w + 32 + lm) * Kin + kq * 8;
    const bf16_t* wrow3 = WT + (size_t)(n0w + 48 + lm) * Kin + kq * 8;

    floatx4 acc[2][4] = {};

    // depth-2 B-frag pipeline
    bf16x8 bc0 = *(const bf16x8*)(wrow0);
    bf16x8 bc1 = *(const bf16x8*)(wrow1);
    bf16x8 bc2 = *(const bf16x8*)(wrow2);
    bf16x8 bc3 = *(const bf16x8*)(wrow3);
    bf16x8 bn0 = bc0, bn1 = bc1, bn2 = bc2, bn3 = bc3;
    if (tsteps > 1) {
        bn0 = *(const bf16x8*)(wrow0 + 32);
        bn1 = *(const bf16x8*)(wrow1 + 32);
        bn2 = *(const bf16x8*)(wrow2 + 32);
        bn3 = *(const bf16x8*)(wrow3 + 32);
    }

    bf16_t* a0 = &As[lm * chunk];
    bf16_t* a1 = &As[(16 + lm) * chunk];
    const int swz = lm & 7;   // note (16+lm)&7 == lm&7, so one swizzle for both

    int s = 0;
    for (int c = 0; c < nch; ++c) {
        __syncthreads();                         // As WAR vs previous chunk
        {   // ---- stage A chunk: row-contiguous global reads ----
            const int kbase = c * chunk;
            const int total = TM << gsh;
            for (int G = t; G < total; G += 256) {
                int row = G >> gsh;
                int g = G & gm;
                int grow = m0 + row;
                int bb = grow / rpb;
                int ii = grow - bb * rpb;
                size_t src = (size_t)(bb * isb + ioff + ii) * Kin + kbase + g * 8;
                bf16x8 v;
                if (a_fp32) {
                    const float* ap = (const float*)A + src;
                    float4 f0 = *(const float4*)ap;
                    float4 f1 = *(const float4*)(ap + 4);
                    v[0]=(bf16_t)f0.x; v[1]=(bf16_t)f0.y; v[2]=(bf16_t)f0.z; v[3]=(bf16_t)f0.w;
                    v[4]=(bf16_t)f1.x; v[5]=(bf16_t)f1.y; v[6]=(bf16_t)f1.z; v[7]=(bf16_t)f1.w;
                } else {
                    v = *(const bf16x8*)((const bf16_t*)A + src);
                }
                *(bf16x8*)&As[row * chunk + ((g ^ (row & 7)) << 3)] = v;
            }
        }
        __syncthreads();                         // As ready
        for (int sl = 0; sl < spc; ++sl, ++s) {
            bf16x8 p0, p1, p2, p3;
            int s2 = s + 2;
            if (s2 < tsteps) {
                int off = s2 * 32;
                p0 = *(const bf16x8*)(wrow0 + off);
                p1 = *(const bf16x8*)(wrow1 + off);
                p2 = *(const bf16x8*)(wrow2 + off);
                p3 = *(const bf16x8*)(wrow3 + off);
            } else { p0 = bc0; p1 = bc1; p2 = bc2; p3 = bc3; }

            int go = (((sl << 2) + kq) ^ swz) << 3;
            bf16x8 af0 = *(const bf16x8*)(a0 + go);
            bf16x8 af1 = *(const bf16x8*)(a1 + go);

            acc[0][0] = __builtin_amdgcn_mfma_f32_16x16x32_bf16(af0, bc0, acc[0][0], 0,0,0);
            acc[1][0] = __builtin_amdgcn_mfma_f32_16x16x32_bf16(af1, bc0, acc[1][0], 0,0,0);
            acc[0][1] = __builtin_amdgcn_mfma_f32_16x16x32_bf16(af0, bc1, acc[0][1], 0,0,0);
            acc[1][1] = __builtin_amdgcn_mfma_f32_16x16x32_bf16(af1, bc1, acc[1][1], 0,0,0);
            acc[0][2] = __builtin_amdgcn_mfma_f32_16x16x32_bf16(af0, bc2, acc[0][2], 0,0,0);
            acc[1][2] = __builtin_amdgcn_mfma_f32_16x16x32_bf16(af1, bc2, acc[1][2], 0,0,0);
            acc[0][3] = __builtin_amdgcn_mfma_f32_16x16x32_bf16(af0, bc3, acc[0][3], 0,0,0);
            acc[1][3] = __builtin_amdgcn_mfma_f32_16x16x32_bf16(af1, bc3, acc[1][3], 0,0,0);

            bc0 = bn0; bc1 = bn1; bc2 = bn2; bc3 = bn3;
            bn0 = p0;  bn1 = p1;  bn2 = p2;  bn3 = p3;
        }
    }

    #pragma unroll
    for (int i = 0; i < 2; ++i)
      #pragma unroll
      for (int j = 0; j < 4; ++j)
        #pragma unroll
        for (int r = 0; r < 4; ++r) {
            int row = m0 + i * 16 + kq * 4 + r;
            int col = n0w + j * 16 + lm;
            int bb = row / rpb, ii = row - bb * rpb;
            float v = acc[i][j][r];
            if (bias) v += (float)bias[col];
            out[(size_t)(bb * osb + ooff + ii) * DI + col] = (bf16_t)v;
        }
}

// ---------------- attention scores --------------------------------------------
__global__ __launch_bounds__(256)
void scores_k(const bf16_t* __restrict__ Wh, int nrows,
              const bf16_t* __restrict__ a_src, const bf16_t* __restrict__ a_dst,
              float* __restrict__ src, float* __restrict__ dst)
{
    int wid  = blockIdx.x * 4 + (threadIdx.x >> 6);
    int lane = threadIdx.x & 63;
    if (wid >= nrows) return;
    bf16x4 wv = *(const bf16x4*)(Wh + (size_t)wid * DI + lane * 4);
    bf16x4 sv = *(const bf16x4*)(a_src + lane * 4);
    bf16x4 dv = *(const bf16x4*)(a_dst + lane * 4);
    float s = 0.f, d = 0.f;
    #pragma unroll
    for (int i = 0; i < 4; ++i) {
        float w = (float)wv[i];
        s += w * (float)sv[i];
        d += w * (float)dv[i];
    }
    #pragma unroll
    for (int off = 32; off > 0; off >>= 1) {
        s += __shfl_down(s, off);
        d += __shfl_down(d, off);
    }
    if (lane == 0) { src[wid] = s; dst[wid] = d; }
}

// ---------------- hub aggregation helpers -------------------------------------
__device__ __forceinline__ float hub20(const bf16_t* __restrict__ Wh,
                                       const float* __restrict__ s,
                                       const float* __restrict__ d,
                                       int b, int c, int e)
{
    int base = b * 63 + 3 + c * 20;
    float ss = s[b * 63 + c];
    float ev[20], mx = -1e30f;
    #pragma unroll
    for (int i = 0; i < 20; ++i) { ev[i] = lrelu_f(ss + d[base + i]); mx = fmaxf(mx, ev[i]); }
    float sw = 0.f, acc = 0.f;
    #pragma unroll
    for (int i = 0; i < 20; ++i) {
        float w = expf(ev[i] - mx);
        sw  += w;
        acc += w * (float)Wh[(size_t)(base + i) * DI + e];
    }
    return acc / sw;
}

__device__ __forceinline__ float hub_tri(const bf16_t* __restrict__ Wh1,
                                         const float* __restrict__ s1,
                                         const float* __restrict__ d1,
                                         int b, int c, int e)
{
    int m0 = (c == 0) ? 1 : 0, m1 = (c == 2) ? 1 : 2;
    float ss = s1[b * 3 + c];
    float e0 = lrelu_f(ss + d1[b * 3 + m0]);
    float e1 = lrelu_f(ss + d1[b * 3 + m1]);
    float mx = fmaxf(e0, e1);
    float w0 = expf(e0 - mx), w1 = expf(e1 - mx);
    return (w0 * (float)Wh1[(size_t)(b * 3 + m0) * DI + e] +
            w1 * (float)Wh1[(size_t)(b * 3 + m1) * DI + e]) / (w0 + w1);
}

// ---------------- stage aggregations ------------------------------------------
__global__ __launch_bounds__(256)
void agg1_k(const bf16_t* __restrict__ Wh1, const float* __restrict__ s1,
            const float* __restrict__ d1, bf16_t* __restrict__ nodes2)
{
    int blk = blockIdx.x;
    int b = blk / 3, n = blk - b * 3;
    int e = threadIdx.x;
    float v = hub_tri(Wh1, s1, d1, b, n, e);
    nodes2[(size_t)(b * 63 + n) * DI + e] = (bf16_t)elu_f(v);
}

__global__ __launch_bounds__(256)
void agg2_k(const bf16_t* __restrict__ Wh1, const bf16_t* __restrict__ Wh2,
            const float* __restrict__ s1, const float* __restrict__ d1,
            const float* __restrict__ s2, const float* __restrict__ d2,
            bf16_t* __restrict__ nodes3)
{
    int blk = blockIdx.x;
    int b = blk / 63, n = blk - b * 63;
    int e = threadIdx.x;
    float v;
    if (n >= 3) {
        int c = (n - 3) / 20;
        v = (float)Wh2[(size_t)(b * 63 + c) * DI + e];
    } else {
        v = hub_tri(Wh1, s1, d1, b, n, e) + hub20(Wh2, s2, d2, b, n, e);
    }
    nodes3[(size_t)(b * 123 + n) * DI + e] = (bf16_t)elu_f(v);
}

__global__ __launch_bounds__(256)
void agg3_k(const bf16_t* __restrict__ Wh1, const bf16_t* __restrict__ Wh2,
            const bf16_t* __restrict__ Wh3,
            const float* __restrict__ s1, const float* __restrict__ d1,
            const float* __restrict__ s2, const float* __restrict__ d2,
            const float* __restrict__ s3, const float* __restrict__ d3,
            float* __restrict__ out)
{
    int blk = blockIdx.x;
    int b = blk / 123, n = blk - b * 123;
    int e = threadIdx.x;
    float v;
    if (n >= 63) {
        int c = (n - 63) / 20;
        v = (float)Wh3[(size_t)(b * 63 + c) * DI + e];
    } else if (n >= 3) {
        int c = (n - 3) / 20;
        v = (float)Wh2[(size_t)(b * 63 + c) * DI + e];
    } else {
        v = hub_tri(Wh1, s1, d1, b, n, e)
          + hub20(Wh2, s2, d2, b, n, e)
          + hub20(Wh3, s3, d3, b, n, e);
    }
    out[(size_t)(b * 123 + n) * DI + e] = elu_f(v);
}

// ------------------------------------------------------------------------------
extern "C" void kernel_launch(void* const* d_in, const int* in_sizes, int n_in,
                              void* d_out, int out_size, void* d_ws, size_t ws_size,
                              hipStream_t stream)
{
    (void)in_sizes; (void)n_in; (void)out_size; (void)ws_size;
    #define INF(i) ((const float*)d_in[i])
    const float *scene_tv=INF(0), *face_tv=INF(1), *text_tv=INF(2),
                *scene_refs=INF(3), *face_refs=INF(4), *text_refs=INF(5),
                *scene_ra=INF(6), *face_ra=INF(7), *text_ra=INF(8),
                *Ws1=INF(9),  *bs1=INF(10), *Wf1=INF(11), *bf1=INF(12),
                *Wt1=INF(13), *bt1=INF(14),
                *G1W=INF(15), *G1as=INF(16), *G1ad=INF(17),
                *Ws2=INF(18), *bs2=INF(19), *Wf2=INF(20), *bf2=INF(21),
                *Wt2=INF(22), *bt2=INF(23),
                *G2W=INF(24), *G2as=INF(25), *G2ad=INF(26),
                *Ws3=INF(27), *bs3=INF(28), *Wf3=INF(29), *bf3=INF(30),
                *Wt3=INF(31), *bt3=INF(32),
                *G3W=INF(33), *G3as=INF(34), *G3ad=INF(35);
    #undef INF

    char* p = (char*)d_ws;
    auto carveB = [&](size_t elems) -> bf16_t* { bf16_t* r = (bf16_t*)p; p += ((elems*2 + 255) & ~(size_t)255); return r; };
    auto carveF = [&](size_t elems) -> float*  { float*  r = (float*)p;  p += ((elems*4 + 255) & ~(size_t)255); return r; };

    bf16_t* Ws1T = carveB(1024*256); bf16_t* Wf1T = carveB(1024*256); bf16_t* Wt1T = carveB(2048*256);
    bf16_t* Ws2T = carveB(1024*256); bf16_t* Wf2T = carveB(1024*256); bf16_t* Wt2T = carveB(2048*256);
    bf16_t* Ws3T = carveB(1024*256); bf16_t* Wf3T = carveB(1024*256); bf16_t* Wt3T = carveB(1024*256);
    bf16_t* G1WT = carveB(256*256);
    bf16_t* G2WT = carveB(2*256*256);
    bf16_t* G3WT = carveB(3*256*256);

    bf16_t* cb[9];
    for (int i = 0; i < 9; ++i) cb[i] = carveB(256);
    bf16_t* a1s = carveB(256); bf16_t* a1d = carveB(256);
    bf16_t* a2s = carveB(512); bf16_t* a2d = carveB(512);
    bf16_t* a3s = carveB(768); bf16_t* a3d = carveB(768);

    bf16_t* nodes1 = carveB((size_t)NB*3*DI);
    bf16_t* nodes2 = carveB((size_t)NB*63*DI);
    bf16_t* nodes3 = carveB((size_t)NB*123*DI);
    bf16_t* Wh1    = carveB((size_t)NB*3*DI);
    bf16_t* Wh2    = carveB((size_t)NB*63*DI);
    bf16_t* Wh3    = carveB((size_t)NB*63*DI);
    float* s1s = carveF(NB*3);  float* s1d = carveF(NB*3);
    float* s2s = carveF(NB*63); float* s2d = carveF(NB*63);
    float* s3s = carveF(NB*63); float* s3d = carveF(NB*63);

    // -------- small conversions --------
    SCArgs sca;
    const float* ssrc[15] = { bs1, bf1, bt1, bs2, bf2, bt2, bs3, bf3, bt3,
                              G1as, G1ad, G2as, G2ad, G3as, G3ad };
    bf16_t* sdst[15] = { cb[0],cb[1],cb[2],cb[3],cb[4],cb[5],cb[6],cb[7],cb[8],
                         a1s, a1d, a2s, a2d, a3s, a3d };
    int sn[15] = { 256,256,256,256,256,256,256,256,256, 256,256,512,512,768,768 };
    for (int i = 0; i < 15; ++i) { sca.e[i].s = ssrc[i]; sca.e[i].d = sdst[i]; sca.e[i].n = sn[i]; }
    sca.cnt = 15;
    smallconv_k<<<1, 256, 0, stream>>>(sca);

    // -------- batched weight transposes --------
    TJobs tj;
    const float* tw[15] = { Ws1, Wf1, Wt1, Ws2, Wf2, Wt2, Ws3, Wf3, Wt3,
                            G1W, G2W, G2W, G3W, G3W, G3W };
    bf16_t* twt[15] = { Ws1T, Wf1T, Wt1T, Ws2T, Wf2T, Wt2T, Ws3T, Wf3T, Wt3T,
                        G1WT, G2WT, G2WT + 65536, G3WT, G3WT + 65536, G3WT + 131072 };
    int tk[15]  = { 1024,1024,2048,1024,1024,2048,1024,1024,1024, 256,256,256,256,256,256 };
    int teo[15] = { 0,0,0,0,0,0,0,0,0, 0,0,65536,0,65536,131072 };
    int tb = 0;
    for (int i = 0; i < 15; ++i) {
        tj.j[i].W = tw[i]; tj.j[i].WT = twt[i]; tj.j[i].K = tk[i];
        tj.j[i].eoff = teo[i]; tj.j[i].tbase = tb;
        tb += (tk[i] >> 5) * 8;
    }
    transpose_all_k<<<tb, 256, 0, stream>>>(tj, 15);

    auto G = [&](const void* A, int Kin, int isb, int ioff, int rpb, int ext,
                 const bf16_t* WT, const bf16_t* bias,
                 bf16_t* out, int osb, int ooff, int M) {
        gemm2_k<<<M / TM, 256, 0, stream>>>(A, Kin, isb, ioff, rpb, ext, WT, bias, out, osb, ooff);
    };
    auto S = [&](const bf16_t* Wh, int nrows, const bf16_t* as_, const bf16_t* ad_,
                 float* s, float* d) {
        scores_k<<<nrows/4, 256, 0, stream>>>(Wh, nrows, as_, ad_, s, d);
    };

    // -------- stage 1 --------
    G(scene_tv, 1024, 1, 0, 1, 1, Ws1T, cb[0], nodes1, 3, 0, NB);
    G(face_tv,  1024, 1, 0, 1, 1, Wf1T, cb[1], nodes1, 3, 1, NB);
    G(text_tv,  2048, 1, 0, 1, 1, Wt1T, cb[2], nodes1, 3, 2, NB);
    G(nodes1, 256, 3, 0, 3, 0, G1WT, nullptr, Wh1, 3, 0, NB*3);
    S(Wh1, NB*3, a1s, a1d, s1s, s1d);
    agg1_k<<<NB*3, 256, 0, stream>>>(Wh1, s1s, s1d, nodes2);

    // -------- stage 2 --------
    G(scene_refs, 1024, 20, 0, 20, 1, Ws2T, cb[3], nodes2, 63,  3, NB*20);
    G(face_refs,  1024, 20, 0, 20, 1, Wf2T, cb[4], nodes2, 63, 23, NB*20);
    G(text_refs,  2048, 20, 0, 20, 1, Wt2T, cb[5], nodes2, 63, 43, NB*20);
    G(nodes2, 256, 63, 0,  3, 0, G2WT,          nullptr, Wh1,  3, 0, NB*3);
    G(nodes2, 256, 63, 0, 63, 0, G2WT + 65536,  nullptr, Wh2, 63, 0, NB*63);
    S(Wh1, NB*3,  a2s,       a2d,       s1s, s1d);
    S(Wh2, NB*63, a2s + 256, a2d + 256, s2s, s2d);
    agg2_k<<<NB*63, 256, 0, stream>>>(Wh1, Wh2, s1s, s1d, s2s, s2d, nodes3);

    // -------- stage 3 --------
    G(scene_ra, 1024, 20, 0, 20, 1, Ws3T, cb[6], nodes3, 123,  63, NB*20);
    G(face_ra,  1024, 20, 0, 20, 1, Wf3T, cb[7], nodes3, 123,  83, NB*20);
    G(text_ra,  1024, 20, 0, 20, 1, Wt3T, cb[8], nodes3, 123, 103, NB*20);
    G(nodes3, 256, 123,  0,  3, 0, G3WT,           nullptr, Wh1,  3, 0, NB*3);
    G(nodes3, 256, 123,  0, 63, 0, G3WT + 65536,   nullptr, Wh2, 63, 0, NB*63);
    G(nodes3, 256, 123,  0,  3, 0, G3WT + 131072,  nullptr, Wh3, 63, 0, NB*3);
    G(nodes3, 256, 123, 63, 60, 0, G3WT + 131072,  nullptr, Wh3, 63, 3, NB*60);
    S(Wh1, NB*3,  a3s,       a3d,       s1s, s1d);
    S(Wh2, NB*63, a3s + 256, a3d + 256, s2s, s2d);
    S(Wh3, NB*63, a3s + 512, a3d + 512, s3s, s3d);
    agg3_k<<<NB*123, 256, 0, stream>>>(Wh1, Wh2, Wh3, s1s, s1d, s2s, s2d, s3s, s3d,
                                       (float*)d_out);
}